// Round 3
// baseline (359.754 us; speedup 1.0000x reference)
//
#include <hip/hip_runtime.h>
#include <hip/hip_bf16.h>

#define HW 16384
#define NPIX 65536
#define CC 256
#define NDIL 16
#define DFF 8
#define CATC 384
#define LNEPS 1e-3f

typedef short bf16x8 __attribute__((ext_vector_type(8)));
typedef float f32x4 __attribute__((ext_vector_type(4)));
typedef int i32x4 __attribute__((ext_vector_type(4)));

typedef const __attribute__((address_space(1))) void* gptr_t;
typedef __attribute__((address_space(3))) void* lptr_t;

__device__ __forceinline__ unsigned short f2bf(float f) {
    unsigned u = __builtin_bit_cast(unsigned, f);
    u += 0x7fffu + ((u >> 16) & 1u);
    return (unsigned short)(u >> 16);
}

// Build the dxo-shifted MFMA A-fragment from two adjacent direct fragments.
// Within each 16-lane DPP row (== our quad group): lane ml gets
//   ml+DXO < 16 ? a[ml+DXO] : b[ml+DXO-16]
// step1: t = row_shr:(16-DXO) of b  (valid in lanes ml >= 16-DXO)
// step2: r = row_shl:DXO of a, OOB lanes (ml > 15-DXO) keep old = t.
template<int DXO>
__device__ __forceinline__ bf16x8 shift_frag(bf16x8 a, bf16x8 b) {
    i32x4 ai = __builtin_bit_cast(i32x4, a);
    i32x4 bi = __builtin_bit_cast(i32x4, b);
    i32x4 r;
    #pragma unroll
    for (int w = 0; w < 4; w++) {
        int t = __builtin_amdgcn_update_dpp(bi[w], bi[w], 0x110 + (16 - DXO), 0xF, 0xF, false);
        r[w] = __builtin_amdgcn_update_dpp(t, ai[w], 0x100 + DXO, 0xF, 0xF, false);
    }
    return __builtin_bit_cast(bf16x8, r);
}

// -------- prep: Wd (dwn bf16 [co][k]); Wbf (smooth bf16 [kc][tap][co][32]);
//          Wb3 (branch kqv bf16 MFMA-B); zero Ssum; zero 1KB zero-page.
__global__ void prep_kernel(const float* __restrict__ dwn_w,
                            const float* __restrict__ smooth_w,
                            const float* __restrict__ k_w, const float* __restrict__ q_w,
                            const float* __restrict__ v_w,
                            unsigned short* __restrict__ Wd, unsigned short* __restrict__ Wbf,
                            unsigned short* __restrict__ Wb3, float* __restrict__ Ssum,
                            float* __restrict__ Zpg) {
    int idx = blockIdx.x * 256 + threadIdx.x;
    if (blockIdx.x == 0 && threadIdx.x < 256) { Ssum[threadIdx.x] = 0.f; Ssum[256 + threadIdx.x] = 0.f; }
    if (blockIdx.x == 1) Zpg[threadIdx.x] = 0.f;     // 1 KB zero page for halo OOB lanes
    if (idx < 128 * 256) {
        int co = idx >> 8, k = idx & 255;
        int i = co >> 3, f = co & 7;
        Wd[idx] = f2bf(dwn_w[(i * 256 + k) * 8 + f]);     // dwn_w [ND][1][1][C][DF]
    }
    int idx2 = idx - 128 * 256;
    if (idx2 >= 0 && idx2 < 12 * 9 * 256 * 32) {
        int k = idx2 & 31;
        int t = idx2 >> 5;
        int co = t & 255;
        int t2 = t >> 8;
        int tap = t2 % 9;
        int kc = t2 / 9;
        int ci = kc * 32 + k;
        Wbf[idx2] = f2bf(smooth_w[(tap * 384 + ci) * 256 + co]); // smooth_w [3][3][CAT][C]
    }
    int idx3 = idx - (128 * 256 + 12 * 9 * 256 * 32);
    if (idx3 >= 0 && idx3 < 16 * 3072) {
        int i = idx3 / 3072, r = idx3 % 3072;
        int kc = r >> 10; r &= 1023;
        int nt = r >> 9;  r &= 511;
        int ncol = r >> 5; r &= 31;
        int quad = r >> 3;
        int j = r & 7;
        int tap = kc * 4 + quad;
        int n = nt * 16 + ncol;
        float val = 0.f;
        if (tap <= 8 && n < 24) {
            int f = n & 7;
            int src = (i * 9 + tap) * 64 + j * 8 + f;    // [ND][3][3][DF][DF]
            val = (n < 8) ? k_w[src] : (n < 16 ? q_w[src] : v_w[src]);
        }
        Wb3[idx3] = f2bf(val);
    }
}

// -------- K1: input LN -> bf16 cat[:,0:256] ----------------------------------------
__global__ void ln_in_kernel(const float* __restrict__ x, const float* __restrict__ g,
                             const float* __restrict__ b, unsigned short* __restrict__ cat) {
    int wid = threadIdx.x >> 6, lane = threadIdx.x & 63;
    int pix = blockIdx.x * 4 + wid;
    float4 v = ((const float4*)(x + (size_t)pix * CC))[lane];
    float s = v.x + v.y + v.z + v.w;
    float ss = v.x * v.x + v.y * v.y + v.z * v.z + v.w * v.w;
    #pragma unroll
    for (int m = 1; m < 64; m <<= 1) { s += __shfl_xor(s, m); ss += __shfl_xor(ss, m); }
    float mean = s * (1.f / 256.f);
    float rstd = rsqrtf(ss * (1.f / 256.f) - mean * mean + LNEPS);
    float4 gv = ((const float4*)g)[lane];
    float4 bv = ((const float4*)b)[lane];
    float4 y;
    y.x = (v.x - mean) * rstd * gv.x + bv.x;
    y.y = (v.y - mean) * rstd * gv.y + bv.y;
    y.z = (v.z - mean) * rstd * gv.z + bv.z;
    y.w = (v.w - mean) * rstd * gv.w + bv.w;
    ushort4* cp = (ushort4*)(cat + (size_t)pix * CATC + lane * 4);
    *cp = make_ushort4(f2bf(y.x), f2bf(y.y), f2bf(y.z), f2bf(y.w));
}

// -------- K2: dwn 1x1 conv bf16 MFMA GEMM; writes TRANSPOSED dxb_t[i][pix][8] -------
__global__ __launch_bounds__(256)
void dwn_mfma_kernel(const unsigned short* __restrict__ cat, const unsigned short* __restrict__ Wd,
                     const float* __restrict__ dwn_b, unsigned short* __restrict__ dxb_t) {
    __shared__ unsigned short Alds[128 * 40];
    int tid = threadIdx.x;
    int wv = tid >> 6, lane = tid & 63;
    int ml = lane & 15, quad = lane >> 4;
    int pb = blockIdx.x * 128;
    f32x4 acc[8][2];
    #pragma unroll
    for (int mi = 0; mi < 8; mi++)
        #pragma unroll
        for (int ni = 0; ni < 2; ni++) acc[mi][ni] = (f32x4){0.f, 0.f, 0.f, 0.f};

    for (int kc = 0; kc < 8; kc++) {
        __syncthreads();
        #pragma unroll
        for (int it = 0; it < 2; it++) {
            int idx = it * 256 + tid;
            int p = idx >> 2, sub = idx & 3;
            uint4 av = *(const uint4*)(cat + (size_t)(pb + p) * CATC + kc * 32 + sub * 8);
            *(uint4*)&Alds[p * 40 + sub * 8] = av;
        }
        __syncthreads();
        bf16x8 bv[2];
        #pragma unroll
        for (int ni = 0; ni < 2; ni++) {
            int co = wv * 32 + ni * 16 + ml;
            bv[ni] = *(const bf16x8*)(Wd + (size_t)co * 256 + kc * 32 + quad * 8);
        }
        bf16x8 af[8];
        #pragma unroll
        for (int mi = 0; mi < 8; mi++)
            af[mi] = *(const bf16x8*)&Alds[(mi * 16 + ml) * 40 + quad * 8];
        #pragma unroll
        for (int mi = 0; mi < 8; mi++)
            #pragma unroll
            for (int ni = 0; ni < 2; ni++)
                acc[mi][ni] = __builtin_amdgcn_mfma_f32_16x16x32_bf16(af[mi], bv[ni], acc[mi][ni], 0, 0, 0);
    }
    float bias[2];
    #pragma unroll
    for (int ni = 0; ni < 2; ni++) bias[ni] = dwn_b[wv * 32 + ni * 16 + ml];
    #pragma unroll
    for (int mi = 0; mi < 8; mi++)
        #pragma unroll
        for (int rg = 0; rg < 4; rg++) {
            int pixel = pb + mi * 16 + quad * 4 + rg;
            #pragma unroll
            for (int ni = 0; ni < 2; ni++) {
                int co = wv * 32 + ni * 16 + ml;
                float v = fmaxf(acc[mi][ni][rg] + bias[ni], 0.f);
                dxb_t[((size_t)(co >> 3) * NPIX + pixel) * 8 + (co & 7)] = f2bf(v);
            }
        }
}

// -------- K3: branch k,q,v dilated 3x3 convs via MFMA (K=tap*8+ci, N=kq|v) ----------
__global__ __launch_bounds__(256)
void branch_conv_kernel(const unsigned short* __restrict__ dxb_t,
                        const unsigned short* __restrict__ Wb3,
                        const float* __restrict__ k_b, const float* __restrict__ q_b,
                        const float* __restrict__ v_b,
                        float* __restrict__ kq_t, float* __restrict__ vbuf_t,
                        float* __restrict__ Ssum) {
    __shared__ unsigned short Slds[3 * 160 * 8];   // 3 dilated rows x 160 halo cols x 8ch
    __shared__ float sred[4][8];
    int i = blockIdx.y;
    int d = i + 1;
    int rowid = blockIdx.x;                 // 0..511
    int n = rowid >> 7, h = rowid & 127;
    int tid = threadIdx.x;
    int wv = tid >> 6, lane = tid & 63;
    int ml = lane & 15, quad = lane >> 4;

    // stage 3 rows (h-d, h, h+d), cols -d..127+d, zeros outside
    #pragma unroll
    for (int it = 0; it < 2; it++) {
        int idx = it * 256 + tid;
        if (idx < 480) {
            int r3 = (idx >= 320) ? 2 : ((idx >= 160) ? 1 : 0);
            int c = idx - r3 * 160;
            int row = h + (r3 - 1) * d;
            int col = c - d;
            uint4 val = make_uint4(0u, 0u, 0u, 0u);
            if ((unsigned)row < 128u && (unsigned)col < 128u)
                val = *(const uint4*)(dxb_t + ((size_t)(i << 16) + (size_t)((n << 14) + (row << 7) + col)) * 8);
            *(uint4*)&Slds[idx * 8] = val;
        }
    }
    __syncthreads();

    // per-lane tap geometry (clamped; pad taps have B=0)
    int tap0 = quad, tap1 = 4 + quad, tap2 = 8;
    int ty0 = tap0 / 3, tx0 = tap0 % 3;
    int ty1 = tap1 / 3, tx1 = tap1 % 3;
    const int ty2 = 2, tx2 = 2;

    // B fragments (L2-resident)
    const unsigned short* wb = Wb3 + i * 3072 + ml * 32 + quad * 8;
    bf16x8 bfrag[3][2];
    #pragma unroll
    for (int kc = 0; kc < 3; kc++)
        #pragma unroll
        for (int nt = 0; nt < 2; nt++)
            bfrag[kc][nt] = *(const bf16x8*)(wb + kc * 1024 + nt * 512);

    f32x4 acc[2][2];
    #pragma unroll
    for (int mt = 0; mt < 2; mt++)
        #pragma unroll
        for (int nt = 0; nt < 2; nt++) acc[mt][nt] = (f32x4){0.f, 0.f, 0.f, 0.f};

    #pragma unroll
    for (int mt = 0; mt < 2; mt++) {
        int m0 = (wv * 2 + mt) * 16 + ml;
        bf16x8 a0 = *(const bf16x8*)&Slds[(ty0 * 160 + m0 + tx0 * d) * 8];
        bf16x8 a1 = *(const bf16x8*)&Slds[(ty1 * 160 + m0 + tx1 * d) * 8];
        bf16x8 a2 = *(const bf16x8*)&Slds[(ty2 * 160 + m0 + tx2 * d) * 8];
        #pragma unroll
        for (int nt = 0; nt < 2; nt++) {
            acc[mt][nt] = __builtin_amdgcn_mfma_f32_16x16x32_bf16(a0, bfrag[0][nt], acc[mt][nt], 0, 0, 0);
            acc[mt][nt] = __builtin_amdgcn_mfma_f32_16x16x32_bf16(a1, bfrag[1][nt], acc[mt][nt], 0, 0, 0);
            acc[mt][nt] = __builtin_amdgcn_mfma_f32_16x16x32_bf16(a2, bfrag[2][nt], acc[mt][nt], 0, 0, 0);
        }
    }

    // epilogue: bias+relu, kq via shfl, stores, exp-sum
    float bkq = (ml < 8) ? k_b[i * 8 + ml] : q_b[i * 8 + (ml & 7)];
    float bvv = (ml < 8) ? v_b[i * 8 + ml] : 0.f;
    float e = 0.f;
    #pragma unroll
    for (int mt = 0; mt < 2; mt++) {
        #pragma unroll
        for (int rg = 0; rg < 4; rg++) {
            float kx = fmaxf(acc[mt][0][rg] + bkq, 0.f);
            float qx = __shfl_xor(kx, 8);
            float kq = kx * qx;
            float vx = fmaxf(acc[mt][1][rg] + bvv, 0.f);
            int p = (wv * 2 + mt) * 16 + quad * 4 + rg;
            if (ml < 8) {
                int hw = h * 128 + p;
                kq_t[((size_t)(n * 128 + i * 8 + ml) << 14) + hw] = kq;
                vbuf_t[((size_t)(i << 16) + (n << 14) + hw) * 8 + ml] = vx;
                e += __expf(kq);
            }
        }
    }
    e += __shfl_xor(e, 16);
    e += __shfl_xor(e, 32);
    if ((lane >> 4) == 0 && ml < 8) sred[wv][ml] = e;
    __syncthreads();
    if (tid < 8) {
        float t = sred[0][tid] + sred[1][tid] + sred[2][tid] + sred[3][tid];
        atomicAdd(&Ssum[n * 128 + i * 8 + tid], t);
    }
}

// -------- K5: attn*v + LN(8) -> cat[:,256:384] bf16 --------------------------------
__global__ void branch_out_kernel(const float* __restrict__ kq_t, const float* __restrict__ vbuf_t,
                                  const float* __restrict__ Ssum,
                                  const float* __restrict__ g_up, const float* __restrict__ b_up,
                                  unsigned short* __restrict__ cat) {
    int i = blockIdx.y;
    int pix = blockIdx.x * 256 + threadIdx.x;
    int n = pix >> 14, hw = pix & 16383;
    float va[8];
    *(float4*)&va[0] = *(const float4*)(vbuf_t + ((size_t)i * NPIX + pix) * 8);
    *(float4*)&va[4] = *(const float4*)(vbuf_t + ((size_t)i * NPIX + pix) * 8 + 4);
    float y[8];
    float s = 0.f, ss = 0.f;
    #pragma unroll
    for (int f = 0; f < 8; f++) {
        int r = n * 128 + i * 8 + f;
        float a = __expf(kq_t[((size_t)r << 14) + hw]) / Ssum[r];
        y[f] = a * va[f];
        s += y[f]; ss += y[f] * y[f];
    }
    float m = s * 0.125f;
    float rstd = rsqrtf(ss * 0.125f - m * m + LNEPS);
    unsigned short o[8];
    #pragma unroll
    for (int f = 0; f < 8; f++) o[f] = f2bf((y[f] - m) * rstd * g_up[f] + b_up[f]);
    ushort4* cp = (ushort4*)(cat + (size_t)pix * CATC + 256 + i * 8);
    cp[0] = make_ushort4(o[0], o[1], o[2], o[3]);
    cp[1] = make_ushort4(o[4], o[5], o[6], o[7]);
}

// -------- K6: smooth 3x3 conv (384->256) -------------------------------------------
// M=128 row/block, grid 512. global_load_lds staging, double-buffered, 1 barrier/kc.
// NEW: per (kc,dy) read only 9 direct A-fragments from LDS (consecutive 16B units);
// the dxo=1,2 tap fragments are built IN-REGISTER via DPP row shifts (2 ops/dword),
// cutting LDS read traffic 72->27 per wave/kc and lgkm waits 9->3 per kc.
// bv weight fragments are rotated 1 tap ahead so L2 latency hides under MFMA issue.
#define SM_UNITS 1600   // 25 wave-groups x 64 units (1560 real + 40 pad)
__global__ __launch_bounds__(256, 2)
void smooth_ln_kernel(const unsigned short* __restrict__ cat, const unsigned short* __restrict__ Wbf,
                      const float* __restrict__ smooth_b, const float* __restrict__ g_out,
                      const float* __restrict__ b_out, const float* __restrict__ Zpg,
                      float* __restrict__ out) {
    __shared__ __align__(16) unsigned short Alds[2][SM_UNITS * 8];   // 2 x 25.6 KB
    __shared__ float pwave[4][128][2];
    __shared__ float mrs[128][2];
    int tid = threadIdx.x;
    int wv = tid >> 6, lane = tid & 63;
    int ml = lane & 15, quad = lane >> 4;
    int rowid = blockIdx.x;                  // 0..511 : (n,h0)
    int n = rowid >> 7, h0 = rowid & 127;
    int pb = rowid * 128;                    // first pixel of this row

    // per-wave staging source offsets (bytes from cat): groups g = wv + 4*s
    const long zoff = (long)((const char*)Zpg - (const char*)cat);
    long goff[7];
    #pragma unroll
    for (int s = 0; s < 7; s++) {
        int g = wv + 4 * s;
        int u = g * 64 + lane;
        int seg = u / 130;                    // q*3 + r
        int c = u - seg * 130;
        int q = seg / 3;
        int r = seg - q * 3;
        int srow = h0 + r - 1;
        int scol = c - 1;
        bool ok = (u < 1560) && ((unsigned)srow < 128u) && ((unsigned)scol < 128u);
        goff[s] = ok ? (long)(((n << 14) + (srow << 7) + scol) * CATC + q * 8) * 2 : zoff;
    }

    f32x4 acc[8][4];
    #pragma unroll
    for (int mi = 0; mi < 8; mi++)
        #pragma unroll
        for (int ni = 0; ni < 4; ni++) acc[mi][ni] = (f32x4){0.f, 0.f, 0.f, 0.f};

    // prologue: stage kc=0 into buffer 0
    #pragma unroll
    for (int s = 0; s < 7; s++) {
        int g = wv + 4 * s;
        if (g < 25)
            __builtin_amdgcn_global_load_lds((gptr_t)((const char*)cat + goff[s]),
                                             (lptr_t)&Alds[0][g * 512], 16, 0, 0);
    }
    __syncthreads();

    const int woff = (wv * 64 + ml) * 32 + quad * 8;   // Wbf lane offset (shorts)
    const int abase = quad * 390;                      // quad*3*130 units
    #pragma unroll 1
    for (int kc = 0; kc < 12; kc++) {
        const int cur = kc & 1;
        // issue next-kc staging BEFORE compute (latency hides under 288 MFMA/wave)
        if (kc < 11) {
            const long koff = (long)(kc + 1) * 64;  // bytes
            #pragma unroll
            for (int s = 0; s < 7; s++) {
                int g = wv + 4 * s;
                if (g < 25)
                    __builtin_amdgcn_global_load_lds((gptr_t)((const char*)cat + goff[s] + koff),
                                                     (lptr_t)&Alds[cur ^ 1][g * 512], 16, 0, 0);
            }
        }
        const unsigned short* Ac = &Alds[cur][0];
        const int kc9 = kc * 9;
        // bv rotation: preload tap 0
        bf16x8 bvn[4];
        #pragma unroll
        for (int ni = 0; ni < 4; ni++)
            bvn[ni] = *(const bf16x8*)(Wbf + (size_t)kc9 * 8192 + ni * 512 + woff);
        #pragma unroll
        for (int dy = 0; dy < 3; dy++) {
            // 9 direct fragments (consecutive units; af0[8] lanes 2..15 unused garbage)
            bf16x8 af0[9];
            #pragma unroll
            for (int mi = 0; mi < 9; mi++)
                af0[mi] = *(const bf16x8*)(Ac + (abase + dy * 130 + mi * 16 + ml) * 8);
            #pragma unroll
            for (int dxo = 0; dxo < 3; dxo++) {
                const int tap = dy * 3 + dxo;
                bf16x8 bv[4];
                #pragma unroll
                for (int ni = 0; ni < 4; ni++) bv[ni] = bvn[ni];
                if (tap < 8) {
                    #pragma unroll
                    for (int ni = 0; ni < 4; ni++)
                        bvn[ni] = *(const bf16x8*)(Wbf + (size_t)(kc9 + tap + 1) * 8192 + ni * 512 + woff);
                }
                #pragma unroll
                for (int mi = 0; mi < 8; mi++) {
                    bf16x8 fr = (dxo == 0) ? af0[mi]
                              : (dxo == 1) ? shift_frag<1>(af0[mi], af0[mi + 1])
                                           : shift_frag<2>(af0[mi], af0[mi + 1]);
                    #pragma unroll
                    for (int ni = 0; ni < 4; ni++)
                        acc[mi][ni] = __builtin_amdgcn_mfma_f32_16x16x32_bf16(fr, bv[ni], acc[mi][ni], 0, 0, 0);
                }
            }
        }
        __syncthreads();   // drains this kc's staging (long since landed)
    }

    // fused bias + relu + LN(256) epilogue
    float sbias[4], gg[4], bb[4];
    #pragma unroll
    for (int ni = 0; ni < 4; ni++) {
        int co = wv * 64 + ni * 16 + ml;
        sbias[ni] = smooth_b[co]; gg[ni] = g_out[co]; bb[ni] = b_out[co];
    }
    #pragma unroll
    for (int mi = 0; mi < 8; mi++) {
        #pragma unroll
        for (int rg = 0; rg < 4; rg++) {
            float s = 0.f, ss = 0.f;
            #pragma unroll
            for (int ni = 0; ni < 4; ni++) {
                float v = fmaxf(acc[mi][ni][rg] + sbias[ni], 0.f);
                s += v; ss += v * v;
            }
            #pragma unroll
            for (int msk = 1; msk < 16; msk <<= 1) { s += __shfl_xor(s, msk); ss += __shfl_xor(ss, msk); }
            if (ml == 0) {
                int P = mi * 16 + quad * 4 + rg;
                pwave[wv][P][0] = s; pwave[wv][P][1] = ss;
            }
        }
    }
    __syncthreads();
    if (tid < 128) {
        float s = pwave[0][tid][0] + pwave[1][tid][0] + pwave[2][tid][0] + pwave[3][tid][0];
        float ss = pwave[0][tid][1] + pwave[1][tid][1] + pwave[2][tid][1] + pwave[3][tid][1];
        float m = s * (1.f / 256.f);
        mrs[tid][0] = m;
        mrs[tid][1] = rsqrtf(ss * (1.f / 256.f) - m * m + LNEPS);
    }
    __syncthreads();
    #pragma unroll
    for (int mi = 0; mi < 8; mi++) {
        #pragma unroll
        for (int rg = 0; rg < 4; rg++) {
            int P = mi * 16 + quad * 4 + rg;
            float m = mrs[P][0], rs = mrs[P][1];
            #pragma unroll
            for (int ni = 0; ni < 4; ni++) {
                float v = fmaxf(acc[mi][ni][rg] + sbias[ni], 0.f);
                out[(size_t)(pb + P) * 256 + wv * 64 + ni * 16 + ml] = (v - m) * rs * gg[ni] + bb[ni];
            }
        }
    }
}

extern "C" void kernel_launch(void* const* d_in, const int* in_sizes, int n_in,
                              void* d_out, int out_size, void* d_ws, size_t ws_size,
                              hipStream_t stream) {
    const float* x        = (const float*)d_in[0];
    const float* dwn_w    = (const float*)d_in[1];
    const float* dwn_b    = (const float*)d_in[2];
    const float* k_w      = (const float*)d_in[3];
    const float* k_b      = (const float*)d_in[4];
    const float* q_w      = (const float*)d_in[5];
    const float* q_b      = (const float*)d_in[6];
    const float* v_w      = (const float*)d_in[7];
    const float* v_b      = (const float*)d_in[8];
    const float* smooth_w = (const float*)d_in[9];
    const float* smooth_b = (const float*)d_in[10];
    const float* ln_in_g  = (const float*)d_in[11];
    const float* ln_in_b  = (const float*)d_in[12];
    const float* ln_up_g  = (const float*)d_in[13];
    const float* ln_up_b  = (const float*)d_in[14];
    const float* ln_out_g = (const float*)d_in[15];
    const float* ln_out_b = (const float*)d_in[16];

    char* ws = (char*)d_ws;
    unsigned short* dxb_t  = (unsigned short*)(ws);                // 16 MB
    float*          kq_t   = (float*)(ws + 16777216);              // 32 MB
    float*          vbuf_t = (float*)(ws + 50331648);              // 32 MB
    unsigned short* cat    = (unsigned short*)(ws + 83886080);     // 48 MB
    float*          Ssum   = (float*)(ws + 134217728);             // 2 KB
    unsigned short* Wd     = (unsigned short*)(ws + 134221824);    // 64 KB
    unsigned short* Wbf    = (unsigned short*)(ws + 134287360);    // 1.73 MB
    unsigned short* Wb3    = (unsigned short*)(ws + 136056832);    // 96 KB
    float*          Zpg    = (float*)(ws + 136155136);             // 1 KB zero page
    float* out = (float*)d_out;

    prep_kernel<<<3776, 256, 0, stream>>>(dwn_w, smooth_w, k_w, q_w, v_w, Wd, Wbf, Wb3, Ssum, Zpg);
    ln_in_kernel<<<16384, 256, 0, stream>>>(x, ln_in_g, ln_in_b, cat);
    dwn_mfma_kernel<<<512, 256, 0, stream>>>(cat, Wd, dwn_b, dxb_t);
    branch_conv_kernel<<<dim3(512, 16), 256, 0, stream>>>(dxb_t, Wb3, k_b, q_b, v_b, kq_t, vbuf_t, Ssum);
    branch_out_kernel<<<dim3(256, 16), 256, 0, stream>>>(kq_t, vbuf_t, Ssum, ln_up_g, ln_up_b, cat);
    smooth_ln_kernel<<<512, 256, 0, stream>>>(cat, Wbf, smooth_b, ln_out_g, ln_out_b, Zpg, out);
}

// Round 5
// 328.040 us; speedup vs baseline: 1.0967x; 1.0967x over previous
//
#include <hip/hip_runtime.h>
#include <hip/hip_bf16.h>

#define HW 16384
#define NPIX 65536
#define CC 256
#define NDIL 16
#define DFF 8
#define CATC 384
#define LNEPS 1e-3f

typedef short bf16x8 __attribute__((ext_vector_type(8)));
typedef float f32x4 __attribute__((ext_vector_type(4)));

__device__ __forceinline__ unsigned short f2bf(float f) {
    unsigned u = __builtin_bit_cast(unsigned, f);
    u += 0x7fffu + ((u >> 16) & 1u);
    return (unsigned short)(u >> 16);
}

__device__ __forceinline__ float bf2f(unsigned short h) {
    return __builtin_bit_cast(float, (unsigned)h << 16);
}

// -------- prep: Wd (dwn bf16 [co][k]); Wbf (smooth bf16 [kc][tap][co][32]);
//          Wb3 (branch kqv bf16 MFMA-B [i][kc3][nt2][ncol16][quad4][j8]); zero Ssum.
__global__ void prep_kernel(const float* __restrict__ dwn_w,
                            const float* __restrict__ smooth_w,
                            const float* __restrict__ k_w, const float* __restrict__ q_w,
                            const float* __restrict__ v_w,
                            unsigned short* __restrict__ Wd, unsigned short* __restrict__ Wbf,
                            unsigned short* __restrict__ Wb3, float* __restrict__ Ssum) {
    int idx = blockIdx.x * 256 + threadIdx.x;
    if (blockIdx.x == 0 && threadIdx.x < 256) { Ssum[threadIdx.x] = 0.f; Ssum[256 + threadIdx.x] = 0.f; }
    if (idx < 128 * 256) {
        int co = idx >> 8, k = idx & 255;
        int i = co >> 3, f = co & 7;
        Wd[idx] = f2bf(dwn_w[(i * 256 + k) * 8 + f]);     // dwn_w [ND][1][1][C][DF]
    }
    int idx2 = idx - 128 * 256;
    if (idx2 >= 0 && idx2 < 12 * 9 * 256 * 32) {
        int k = idx2 & 31;
        int t = idx2 >> 5;
        int co = t & 255;
        int t2 = t >> 8;
        int tap = t2 % 9;
        int kc = t2 / 9;
        int ci = kc * 32 + k;
        Wbf[idx2] = f2bf(smooth_w[(tap * 384 + ci) * 256 + co]); // smooth_w [3][3][CAT][C]
    }
    int idx3 = idx - (128 * 256 + 12 * 9 * 256 * 32);
    if (idx3 >= 0 && idx3 < 16 * 3072) {
        int i = idx3 / 3072, r = idx3 % 3072;
        int kc = r >> 10; r &= 1023;
        int nt = r >> 9;  r &= 511;
        int ncol = r >> 5; r &= 31;
        int quad = r >> 3;
        int j = r & 7;
        int tap = kc * 4 + quad;
        int n = nt * 16 + ncol;
        float val = 0.f;
        if (tap <= 8 && n < 24) {
            int f = n & 7;
            int src = (i * 9 + tap) * 64 + j * 8 + f;    // [ND][3][3][DF][DF]
            val = (n < 8) ? k_w[src] : (n < 16 ? q_w[src] : v_w[src]);
        }
        Wb3[idx3] = f2bf(val);
    }
}

// -------- K1: input LN -> bf16 cat[:,0:256] ----------------------------------------
__global__ void ln_in_kernel(const float* __restrict__ x, const float* __restrict__ g,
                             const float* __restrict__ b, unsigned short* __restrict__ cat) {
    int wid = threadIdx.x >> 6, lane = threadIdx.x & 63;
    int pix = blockIdx.x * 4 + wid;
    float4 v = ((const float4*)(x + (size_t)pix * CC))[lane];
    float s = v.x + v.y + v.z + v.w;
    float ss = v.x * v.x + v.y * v.y + v.z * v.z + v.w * v.w;
    #pragma unroll
    for (int m = 1; m < 64; m <<= 1) { s += __shfl_xor(s, m); ss += __shfl_xor(ss, m); }
    float mean = s * (1.f / 256.f);
    float rstd = rsqrtf(ss * (1.f / 256.f) - mean * mean + LNEPS);
    float4 gv = ((const float4*)g)[lane];
    float4 bv = ((const float4*)b)[lane];
    float4 y;
    y.x = (v.x - mean) * rstd * gv.x + bv.x;
    y.y = (v.y - mean) * rstd * gv.y + bv.y;
    y.z = (v.z - mean) * rstd * gv.z + bv.z;
    y.w = (v.w - mean) * rstd * gv.w + bv.w;
    ushort4* cp = (ushort4*)(cat + (size_t)pix * CATC + lane * 4);
    *cp = make_ushort4(f2bf(y.x), f2bf(y.y), f2bf(y.z), f2bf(y.w));
}

// -------- K2: dwn 1x1 conv bf16 MFMA GEMM; writes TRANSPOSED dxb_t[i][pix][8] -------
__global__ __launch_bounds__(256)
void dwn_mfma_kernel(const unsigned short* __restrict__ cat, const unsigned short* __restrict__ Wd,
                     const float* __restrict__ dwn_b, unsigned short* __restrict__ dxb_t) {
    __shared__ unsigned short Alds[128 * 40];
    int tid = threadIdx.x;
    int wv = tid >> 6, lane = tid & 63;
    int ml = lane & 15, quad = lane >> 4;
    int pb = blockIdx.x * 128;
    f32x4 acc[8][2];
    #pragma unroll
    for (int mi = 0; mi < 8; mi++)
        #pragma unroll
        for (int ni = 0; ni < 2; ni++) acc[mi][ni] = (f32x4){0.f, 0.f, 0.f, 0.f};

    for (int kc = 0; kc < 8; kc++) {
        __syncthreads();
        #pragma unroll
        for (int it = 0; it < 2; it++) {
            int idx = it * 256 + tid;
            int p = idx >> 2, sub = idx & 3;
            uint4 av = *(const uint4*)(cat + (size_t)(pb + p) * CATC + kc * 32 + sub * 8);
            *(uint4*)&Alds[p * 40 + sub * 8] = av;
        }
        __syncthreads();
        bf16x8 bv[2];
        #pragma unroll
        for (int ni = 0; ni < 2; ni++) {
            int co = wv * 32 + ni * 16 + ml;
            bv[ni] = *(const bf16x8*)(Wd + (size_t)co * 256 + kc * 32 + quad * 8);
        }
        bf16x8 af[8];
        #pragma unroll
        for (int mi = 0; mi < 8; mi++)
            af[mi] = *(const bf16x8*)&Alds[(mi * 16 + ml) * 40 + quad * 8];
        #pragma unroll
        for (int mi = 0; mi < 8; mi++)
            #pragma unroll
            for (int ni = 0; ni < 2; ni++)
                acc[mi][ni] = __builtin_amdgcn_mfma_f32_16x16x32_bf16(af[mi], bv[ni], acc[mi][ni], 0, 0, 0);
    }
    float bias[2];
    #pragma unroll
    for (int ni = 0; ni < 2; ni++) bias[ni] = dwn_b[wv * 32 + ni * 16 + ml];
    #pragma unroll
    for (int mi = 0; mi < 8; mi++)
        #pragma unroll
        for (int rg = 0; rg < 4; rg++) {
            int pixel = pb + mi * 16 + quad * 4 + rg;
            #pragma unroll
            for (int ni = 0; ni < 2; ni++) {
                int co = wv * 32 + ni * 16 + ml;
                float v = fmaxf(acc[mi][ni][rg] + bias[ni], 0.f);
                dxb_t[((size_t)(co >> 3) * NPIX + pixel) * 8 + (co & 7)] = f2bf(v);
            }
        }
}

// -------- K3: branch k,q,v dilated 3x3 convs via MFMA (K=tap*8+ci, N=kq|v) ----------
// block = (one image row, one branch); 4 waves; M=128 px; fused relu(k)relu(q), exp-sum
// vbuf_t now stored as bf16 (halves its write+read traffic; v is bf16-bound anyway).
__global__ __launch_bounds__(256)
void branch_conv_kernel(const unsigned short* __restrict__ dxb_t,
                        const unsigned short* __restrict__ Wb3,
                        const float* __restrict__ k_b, const float* __restrict__ q_b,
                        const float* __restrict__ v_b,
                        float* __restrict__ kq_t, unsigned short* __restrict__ vbuf_t,
                        float* __restrict__ Ssum) {
    __shared__ unsigned short Slds[3 * 160 * 8];   // 3 dilated rows x 160 halo cols x 8ch
    __shared__ float sred[4][8];
    int i = blockIdx.y;
    int d = i + 1;
    int rowid = blockIdx.x;                 // 0..511
    int n = rowid >> 7, h = rowid & 127;
    int tid = threadIdx.x;
    int wv = tid >> 6, lane = tid & 63;
    int ml = lane & 15, quad = lane >> 4;

    // stage 3 rows (h-d, h, h+d), cols -d..127+d, zeros outside
    #pragma unroll
    for (int it = 0; it < 2; it++) {
        int idx = it * 256 + tid;
        if (idx < 480) {
            int r3 = (idx >= 320) ? 2 : ((idx >= 160) ? 1 : 0);
            int c = idx - r3 * 160;
            int row = h + (r3 - 1) * d;
            int col = c - d;
            uint4 val = make_uint4(0u, 0u, 0u, 0u);
            if ((unsigned)row < 128u && (unsigned)col < 128u)
                val = *(const uint4*)(dxb_t + ((size_t)(i << 16) + (size_t)((n << 14) + (row << 7) + col)) * 8);
            *(uint4*)&Slds[idx * 8] = val;
        }
    }
    __syncthreads();

    // per-lane tap geometry (clamped; pad taps have B=0)
    int tap0 = quad, tap1 = 4 + quad, tap2 = 8;
    int ty0 = tap0 / 3, tx0 = tap0 % 3;
    int ty1 = tap1 / 3, tx1 = tap1 % 3;
    const int ty2 = 2, tx2 = 2;

    // B fragments (L2-resident)
    const unsigned short* wb = Wb3 + i * 3072 + ml * 32 + quad * 8;
    bf16x8 bfrag[3][2];
    #pragma unroll
    for (int kc = 0; kc < 3; kc++)
        #pragma unroll
        for (int nt = 0; nt < 2; nt++)
            bfrag[kc][nt] = *(const bf16x8*)(wb + kc * 1024 + nt * 512);

    f32x4 acc[2][2];
    #pragma unroll
    for (int mt = 0; mt < 2; mt++)
        #pragma unroll
        for (int nt = 0; nt < 2; nt++) acc[mt][nt] = (f32x4){0.f, 0.f, 0.f, 0.f};

    #pragma unroll
    for (int mt = 0; mt < 2; mt++) {
        int m0 = (wv * 2 + mt) * 16 + ml;
        bf16x8 a0 = *(const bf16x8*)&Slds[(ty0 * 160 + m0 + tx0 * d) * 8];
        bf16x8 a1 = *(const bf16x8*)&Slds[(ty1 * 160 + m0 + tx1 * d) * 8];
        bf16x8 a2 = *(const bf16x8*)&Slds[(ty2 * 160 + m0 + tx2 * d) * 8];
        #pragma unroll
        for (int nt = 0; nt < 2; nt++) {
            acc[mt][nt] = __builtin_amdgcn_mfma_f32_16x16x32_bf16(a0, bfrag[0][nt], acc[mt][nt], 0, 0, 0);
            acc[mt][nt] = __builtin_amdgcn_mfma_f32_16x16x32_bf16(a1, bfrag[1][nt], acc[mt][nt], 0, 0, 0);
            acc[mt][nt] = __builtin_amdgcn_mfma_f32_16x16x32_bf16(a2, bfrag[2][nt], acc[mt][nt], 0, 0, 0);
        }
    }

    // epilogue: bias+relu, kq via shfl, stores, exp-sum
    float bkq = (ml < 8) ? k_b[i * 8 + ml] : q_b[i * 8 + (ml & 7)];
    float bvv = (ml < 8) ? v_b[i * 8 + ml] : 0.f;
    float e = 0.f;
    #pragma unroll
    for (int mt = 0; mt < 2; mt++) {
        #pragma unroll
        for (int rg = 0; rg < 4; rg++) {
            float kx = fmaxf(acc[mt][0][rg] + bkq, 0.f);
            float qx = __shfl_xor(kx, 8);
            float kq = kx * qx;
            float vx = fmaxf(acc[mt][1][rg] + bvv, 0.f);
            int p = (wv * 2 + mt) * 16 + quad * 4 + rg;
            if (ml < 8) {
                int hw = h * 128 + p;
                kq_t[((size_t)(n * 128 + i * 8 + ml) << 14) + hw] = kq;
                vbuf_t[((size_t)(i << 16) + (n << 14) + hw) * 8 + ml] = f2bf(vx);
                e += __expf(kq);
            }
        }
    }
    e += __shfl_xor(e, 16);
    e += __shfl_xor(e, 32);
    if ((lane >> 4) == 0 && ml < 8) sred[wv][ml] = e;
    __syncthreads();
    if (tid < 8) {
        float t = sred[0][tid] + sred[1][tid] + sred[2][tid] + sred[3][tid];
        atomicAdd(&Ssum[n * 128 + i * 8 + tid], t);
    }
}

// -------- K5: attn*v + LN(8) -> cat[:,256:384] bf16 --------------------------------
__global__ void branch_out_kernel(const float* __restrict__ kq_t, const unsigned short* __restrict__ vbuf_t,
                                  const float* __restrict__ Ssum,
                                  const float* __restrict__ g_up, const float* __restrict__ b_up,
                                  unsigned short* __restrict__ cat) {
    int i = blockIdx.y;
    int pix = blockIdx.x * 256 + threadIdx.x;
    int n = pix >> 14, hw = pix & 16383;
    uint4 vw = *(const uint4*)(vbuf_t + ((size_t)i * NPIX + pix) * 8);   // 8 bf16
    float va[8];
    va[0] = __builtin_bit_cast(float, vw.x << 16);
    va[1] = __builtin_bit_cast(float, vw.x & 0xffff0000u);
    va[2] = __builtin_bit_cast(float, vw.y << 16);
    va[3] = __builtin_bit_cast(float, vw.y & 0xffff0000u);
    va[4] = __builtin_bit_cast(float, vw.z << 16);
    va[5] = __builtin_bit_cast(float, vw.z & 0xffff0000u);
    va[6] = __builtin_bit_cast(float, vw.w << 16);
    va[7] = __builtin_bit_cast(float, vw.w & 0xffff0000u);
    float y[8];
    float s = 0.f, ss = 0.f;
    #pragma unroll
    for (int f = 0; f < 8; f++) {
        int r = n * 128 + i * 8 + f;
        float a = __expf(kq_t[((size_t)r << 14) + hw]) / Ssum[r];
        y[f] = a * va[f];
        s += y[f]; ss += y[f] * y[f];
    }
    float m = s * 0.125f;
    float rstd = rsqrtf(ss * 0.125f - m * m + LNEPS);
    unsigned short o[8];
    #pragma unroll
    for (int f = 0; f < 8; f++) o[f] = f2bf((y[f] - m) * rstd * g_up[f] + b_up[f]);
    ushort4* cp = (ushort4*)(cat + (size_t)pix * CATC + 256 + i * 8);
    cp[0] = make_ushort4(o[0], o[1], o[2], o[3]);
    cp[1] = make_ushort4(o[4], o[5], o[6], o[7]);
}

// -------- K6: smooth 3x3 conv (384->256), M=128 row, neighborhood LDS, B via L2 -----
__global__ __launch_bounds__(256, 2)
void smooth_ln_kernel(const unsigned short* __restrict__ cat, const unsigned short* __restrict__ Wbf,
                      const float* __restrict__ smooth_b, const float* __restrict__ g_out,
                      const float* __restrict__ b_out, float* __restrict__ out) {
    __shared__ unsigned short Alds[3 * 130 * 40];   // 3 rows x 130 halo-cols x 32ch (pad 40)
    __shared__ float pwave[4][128][2];
    __shared__ float mrs[128][2];
    int tid = threadIdx.x;
    int wv = tid >> 6, lane = tid & 63;
    int ml = lane & 15, quad = lane >> 4;
    int rowid = blockIdx.x;                  // 0..511 : (n,h)
    int n = rowid >> 7, h0 = rowid & 127;
    int pb = rowid * 128;                    // first pixel of this row

    float sbias[4], gg[4], bb[4];
    #pragma unroll
    for (int ni = 0; ni < 4; ni++) {
        int co = wv * 64 + ni * 16 + ml;
        sbias[ni] = smooth_b[co]; gg[ni] = g_out[co]; bb[ni] = b_out[co];
    }
    f32x4 acc[8][4];
    #pragma unroll
    for (int mi = 0; mi < 8; mi++)
        #pragma unroll
        for (int ni = 0; ni < 4; ni++) acc[mi][ni] = (f32x4){0.f, 0.f, 0.f, 0.f};

    for (int kc = 0; kc < 12; kc++) {
        __syncthreads();
        // stage 3x130 neighborhood, 32 channels
        for (int it = 0; it < 7; it++) {
            int idx = it * 256 + tid;
            if (idx < 1560) {
                int r3 = (idx >= 1040) ? 2 : ((idx >= 520) ? 1 : 0);
                int rem = idx - r3 * 520;
                int c130 = rem >> 2, sub = rem & 3;
                int srow = h0 + r3 - 1, scol = c130 - 1;
                uint4 av = make_uint4(0u, 0u, 0u, 0u);
                if ((unsigned)srow < 128u && (unsigned)scol < 128u)
                    av = *(const uint4*)(cat + (size_t)((n << 14) + srow * 128 + scol) * CATC + kc * 32 + sub * 8);
                *(uint4*)&Alds[(r3 * 130 + c130) * 40 + sub * 8] = av;
            }
        }
        __syncthreads();
        #pragma unroll
        for (int tap = 0; tap < 9; tap++) {
            const int dy = tap / 3, dxo = tap % 3;
            bf16x8 bv[4];
            #pragma unroll
            for (int ni = 0; ni < 4; ni++)
                bv[ni] = *(const bf16x8*)(Wbf + ((size_t)((kc * 9 + tap) * 256 + wv * 64 + ni * 16 + ml)) * 32 + quad * 8);
            bf16x8 af[8];
            #pragma unroll
            for (int mi = 0; mi < 8; mi++)
                af[mi] = *(const bf16x8*)&Alds[(dy * 130 + mi * 16 + ml + dxo) * 40 + quad * 8];
            #pragma unroll
            for (int mi = 0; mi < 8; mi++)
                #pragma unroll
                for (int ni = 0; ni < 4; ni++)
                    acc[mi][ni] = __builtin_amdgcn_mfma_f32_16x16x32_bf16(af[mi], bv[ni], acc[mi][ni], 0, 0, 0);
        }
    }
    // fused bias + relu + LN(256) epilogue
    #pragma unroll
    for (int mi = 0; mi < 8; mi++) {
        #pragma unroll
        for (int rg = 0; rg < 4; rg++) {
            float s = 0.f, ss = 0.f;
            #pragma unroll
            for (int ni = 0; ni < 4; ni++) {
                float v = fmaxf(acc[mi][ni][rg] + sbias[ni], 0.f);
                s += v; ss += v * v;
            }
            #pragma unroll
            for (int msk = 1; msk < 16; msk <<= 1) { s += __shfl_xor(s, msk); ss += __shfl_xor(ss, msk); }
            if (ml == 0) {
                int P = mi * 16 + quad * 4 + rg;
                pwave[wv][P][0] = s; pwave[wv][P][1] = ss;
            }
        }
    }
    __syncthreads();
    if (tid < 128) {
        float s = pwave[0][tid][0] + pwave[1][tid][0] + pwave[2][tid][0] + pwave[3][tid][0];
        float ss = pwave[0][tid][1] + pwave[1][tid][1] + pwave[2][tid][1] + pwave[3][tid][1];
        float m = s * (1.f / 256.f);
        mrs[tid][0] = m;
        mrs[tid][1] = rsqrtf(ss * (1.f / 256.f) - m * m + LNEPS);
    }
    __syncthreads();
    #pragma unroll
    for (int mi = 0; mi < 8; mi++) {
        #pragma unroll
        for (int rg = 0; rg < 4; rg++) {
            int P = mi * 16 + quad * 4 + rg;
            float m = mrs[P][0], rs = mrs[P][1];
            #pragma unroll
            for (int ni = 0; ni < 4; ni++) {
                float v = fmaxf(acc[mi][ni][rg] + sbias[ni], 0.f);
                out[(size_t)(pb + P) * 256 + wv * 64 + ni * 16 + ml] = (v - m) * rs * gg[ni] + bb[ni];
            }
        }
    }
}

extern "C" void kernel_launch(void* const* d_in, const int* in_sizes, int n_in,
                              void* d_out, int out_size, void* d_ws, size_t ws_size,
                              hipStream_t stream) {
    const float* x        = (const float*)d_in[0];
    const float* dwn_w    = (const float*)d_in[1];
    const float* dwn_b    = (const float*)d_in[2];
    const float* k_w      = (const float*)d_in[3];
    const float* k_b      = (const float*)d_in[4];
    const float* q_w      = (const float*)d_in[5];
    const float* q_b      = (const float*)d_in[6];
    const float* v_w      = (const float*)d_in[7];
    const float* v_b      = (const float*)d_in[8];
    const float* smooth_w = (const float*)d_in[9];
    const float* smooth_b = (const float*)d_in[10];
    const float* ln_in_g  = (const float*)d_in[11];
    const float* ln_in_b  = (const float*)d_in[12];
    const float* ln_up_g  = (const float*)d_in[13];
    const float* ln_up_b  = (const float*)d_in[14];
    const float* ln_out_g = (const float*)d_in[15];
    const float* ln_out_b = (const float*)d_in[16];

    char* ws = (char*)d_ws;
    unsigned short* dxb_t  = (unsigned short*)(ws);                // 16 MB
    float*          kq_t   = (float*)(ws + 16777216);              // 32 MB
    unsigned short* vbuf_t = (unsigned short*)(ws + 50331648);     // 16 MB used (32 reserved)
    unsigned short* cat    = (unsigned short*)(ws + 83886080);     // 48 MB
    float*          Ssum   = (float*)(ws + 134217728);             // 2 KB
    unsigned short* Wd     = (unsigned short*)(ws + 134221824);    // 64 KB
    unsigned short* Wbf    = (unsigned short*)(ws + 134287360);    // 1.73 MB
    unsigned short* Wb3    = (unsigned short*)(ws + 136056832);    // 96 KB
    float* out = (float*)d_out;

    prep_kernel<<<3776, 256, 0, stream>>>(dwn_w, smooth_w, k_w, q_w, v_w, Wd, Wbf, Wb3, Ssum);
    ln_in_kernel<<<16384, 256, 0, stream>>>(x, ln_in_g, ln_in_b, cat);
    dwn_mfma_kernel<<<512, 256, 0, stream>>>(cat, Wd, dwn_b, dxb_t);
    branch_conv_kernel<<<dim3(512, 16), 256, 0, stream>>>(dxb_t, Wb3, k_b, q_b, v_b, kq_t, vbuf_t, Ssum);
    branch_out_kernel<<<dim3(256, 16), 256, 0, stream>>>(kq_t, vbuf_t, Ssum, ln_up_g, ln_up_b, cat);
    smooth_ln_kernel<<<512, 256, 0, stream>>>(cat, Wbf, smooth_b, ln_out_g, ln_out_b, out);
}